// Round 1
// baseline (346.079 us; speedup 1.0000x reference)
//
#include <hip/hip_runtime.h>
#include <math.h>

#define T_DIM 2048
#define B_DIM 2
#define D_DIM 256
#define TC 512
#define KV_LEN 2560   // TC + T

__device__ __forceinline__ float wave_sum64(float v) {
#pragma unroll
    for (int off = 32; off > 0; off >>= 1) v += __shfl_xor(v, off, 64);
    return v;
}

__device__ __forceinline__ float rope_angle(int pos, int j) {
    // inv_freq = 1/10000^(j/32), fp32 like the reference
    float inv = powf(10000.0f, -(float)j * (1.0f / 32.0f));
    return (float)pos * inv;
}

// ---------------------------------------------------------------------------
// K1: per-token — H_dc, Q_I, W_Iw, Q (rms+g+rope), sliding K/V (rms+g+rope)
// 4 tokens per block, one wave per token.
// ---------------------------------------------------------------------------
__global__ __launch_bounds__(256) void k_pertoken(
    const float* __restrict__ H, const float* __restrict__ W_DQ,
    const float* __restrict__ W_IUQ, const float* __restrict__ W_w,
    const float* __restrict__ W_Q, const float* __restrict__ W_KV,
    const float* __restrict__ g_q, const float* __restrict__ g_k,
    const float* __restrict__ g_v,
    float* __restrict__ QI, float* __restrict__ Wiw, float* __restrict__ Qr,
    float* __restrict__ Kbuf, float* __restrict__ Vbuf)
{
    int wv = threadIdx.x >> 6;
    int lane = threadIdx.x & 63;
    int bt = blockIdx.x * 4 + wv;
    int b = bt >> 11;
    int t = bt & 2047;

    __shared__ float sH[4][256];
    __shared__ float sHdc[4][64];

    const float* Hrow = H + (size_t)bt * D_DIM;
    *(float4*)(&sH[wv][lane * 4]) = *(const float4*)(Hrow + lane * 4);
    __syncthreads();

    // H_dc = H @ W_DQ (64)
    float hdc = 0.f;
#pragma unroll 8
    for (int i = 0; i < 256; ++i) hdc = fmaf(sH[wv][i], W_DQ[i * 64 + lane], hdc);
    sHdc[wv][lane] = hdc;
    __syncthreads();

    // Q_I = H_dc @ W_IUQ (128), 2 cols per lane
    {
        float a0 = 0.f, a1 = 0.f;
#pragma unroll 8
        for (int jj = 0; jj < 64; ++jj) {
            float hv = sHdc[wv][jj];
            a0 = fmaf(hv, W_IUQ[jj * 128 + lane], a0);
            a1 = fmaf(hv, W_IUQ[jj * 128 + 64 + lane], a1);
        }
        QI[(size_t)bt * 128 + lane] = a0;
        QI[(size_t)bt * 128 + 64 + lane] = a1;
    }
    if (lane < 4) {
        float aw = 0.f;
        for (int jj = 0; jj < 64; ++jj) aw = fmaf(sHdc[wv][jj], W_w[jj * 4 + lane], aw);
        Wiw[(size_t)bt * 4 + lane] = aw;
    }

    int j = lane & 31;
    float s_t, c_t;
    sincosf(rope_angle(t, j), &s_t, &c_t);

    // Q = H @ W_Q (256 cols = 4 heads x 64), rms per head, * g_q, rope(t)
    {
        float qv[4];
#pragma unroll
        for (int r = 0; r < 4; ++r) qv[r] = 0.f;
        for (int i = 0; i < 256; ++i) {
            float hv = sH[wv][i];
            const float* wr = W_Q + (size_t)i * 256;
#pragma unroll
            for (int r = 0; r < 4; ++r) qv[r] = fmaf(hv, wr[r * 64 + lane], qv[r]);
        }
#pragma unroll
        for (int r = 0; r < 4; ++r) {
            float ss = wave_sum64(qv[r] * qv[r]);
            float sc = rsqrtf(ss * (1.0f / 64.0f) + 1e-6f);
            float q = qv[r] * sc * g_q[r * 64 + lane];
            float prt = __shfl_xor(q, 32, 64);
            float o = (lane < 32) ? fmaf(q, c_t, -prt * s_t)
                                  : fmaf(prt, s_t, q * c_t);
            Qr[(size_t)bt * 256 + r * 64 + lane] = o;
        }
    }

    // sliding KV = H @ W_KV (64), rms, g_k/g_v, rope at pos TC+t
    {
        float kvv = 0.f;
#pragma unroll 8
        for (int i = 0; i < 256; ++i) kvv = fmaf(sH[wv][i], W_KV[i * 64 + lane], kvv);
        float ss = wave_sum64(kvv * kvv);
        float sc = rsqrtf(ss * (1.0f / 64.0f) + 1e-6f);
        float kk = kvv * sc * g_k[lane];
        float vvv = kvv * sc * g_v[lane];
        int pos = TC + t;
        float s_p, c_p;
        sincosf(rope_angle(pos, j), &s_p, &c_p);
        float pk = __shfl_xor(kk, 32, 64);
        float pv = __shfl_xor(vvv, 32, 64);
        float ko = (lane < 32) ? fmaf(kk, c_p, -pk * s_p) : fmaf(pk, s_p, kk * c_p);
        float vo = (lane < 32) ? fmaf(vvv, c_p, -pv * s_p) : fmaf(pv, s_p, vvv * c_p);
        size_t off = ((size_t)b * KV_LEN + pos) * 64 + lane;
        Kbuf[off] = ko;
        Vbuf[off] = vo;
    }
}

// ---------------------------------------------------------------------------
// K2: compressed tokens — K_I = win@Wc_idx (32), KVc = win@Wc_comp (64),
// then rms+g+rope at pos s. 4 compressed tokens per block, wave per token.
// ---------------------------------------------------------------------------
__global__ __launch_bounds__(256) void k_compress(
    const float* __restrict__ H, const float* __restrict__ Wc_comp,
    const float* __restrict__ Wc_idx, const float* __restrict__ g_k,
    const float* __restrict__ g_v,
    float* __restrict__ KIbuf, float* __restrict__ Kbuf, float* __restrict__ Vbuf)
{
    int wv = threadIdx.x >> 6;
    int lane = threadIdx.x & 63;
    int bs = blockIdx.x * 4 + wv;
    int b = bs >> 9;
    int s = bs & 511;

    __shared__ float sW[4][2048];
#pragma unroll
    for (int rr = 0; rr < 8; ++rr) {
        int row = 4 * s + rr;
        float4 v = make_float4(0.f, 0.f, 0.f, 0.f);
        if (row < T_DIM) v = *(const float4*)(H + ((size_t)b * T_DIM + row) * D_DIM + lane * 4);
        *(float4*)(&sW[wv][rr * 256 + lane * 4]) = v;
    }
    __syncthreads();

    // K_I: 32 cols; split the 2048-sum across the two half-waves
    {
        int col = lane & 31;
        int half = lane >> 5;
        float a = 0.f;
        int w0 = half * 1024;
#pragma unroll 8
        for (int w2 = w0; w2 < w0 + 1024; ++w2)
            a = fmaf(sW[wv][w2], Wc_idx[(size_t)w2 * 32 + col], a);
        a += __shfl_xor(a, 32, 64);
        if (lane < 32) KIbuf[(size_t)b * TC * 32 + s * 32 + col] = a;
    }

    // KVc: 64 cols
    float kvv = 0.f;
#pragma unroll 8
    for (int w2 = 0; w2 < 2048; ++w2)
        kvv = fmaf(sW[wv][w2], Wc_comp[(size_t)w2 * 64 + lane], kvv);

    float ss = wave_sum64(kvv * kvv);
    float sc = rsqrtf(ss * (1.0f / 64.0f) + 1e-6f);
    float kk = kvv * sc * g_k[lane];
    float vvv = kvv * sc * g_v[lane];
    int j = lane & 31;
    float sa, ca;
    sincosf(rope_angle(s, j), &sa, &ca);
    float pk = __shfl_xor(kk, 32, 64);
    float pv = __shfl_xor(vvv, 32, 64);
    float ko = (lane < 32) ? fmaf(kk, ca, -pk * sa) : fmaf(pk, sa, kk * ca);
    float vo = (lane < 32) ? fmaf(vvv, ca, -pv * sa) : fmaf(pv, sa, vvv * ca);
    size_t off = ((size_t)b * KV_LEN + s) * 64 + lane;
    Kbuf[off] = ko;
    Vbuf[off] = vo;
}

// ---------------------------------------------------------------------------
// K4: index scores I_ts + exact top-8 (jax.lax.top_k semantics: value desc,
// index asc; invalid (4s>t) = -inf but still selectable by index order).
// 4 tokens per block, wave per token; lane holds 8 s-slots (512/64).
// ---------------------------------------------------------------------------
__global__ __launch_bounds__(256) void k_score_topk(
    const float* __restrict__ QI, const float* __restrict__ Wiw,
    const float* __restrict__ KIbuf, int* __restrict__ topk)
{
    int wv = threadIdx.x >> 6;
    int lane = threadIdx.x & 63;
    int bt = blockIdx.x * 4 + wv;
    int b = bt >> 11;
    int t = bt & 2047;

    __shared__ float sQ[4][128];
    __shared__ float sw[4][4];
    sQ[wv][lane] = QI[(size_t)bt * 128 + lane];
    sQ[wv][64 + lane] = QI[(size_t)bt * 128 + 64 + lane];
    if (lane < 4) sw[wv][lane] = Wiw[(size_t)bt * 4 + lane];
    __syncthreads();

    const float* KIb = KIbuf + (size_t)b * TC * 32;
    int smax = t >> 2;  // valid: 4s <= t
    float vals[8];
#pragma unroll
    for (int r = 0; r < 8; ++r) {
        int s = lane + 64 * r;
        float v = -INFINITY;
        if (s <= smax) {
            const float* kr = KIb + s * 32;
            float acc = 0.f;
#pragma unroll
            for (int h2 = 0; h2 < 4; ++h2) {
                float dd = 0.f;
#pragma unroll
                for (int c = 0; c < 32; ++c) dd = fmaf(sQ[wv][h2 * 32 + c], kr[c], dd);
                acc = fmaf(sw[wv][h2], fmaxf(dd, 0.f), acc);
            }
            v = acc;
        }
        vals[r] = v;
    }

    unsigned consumed = 0u;
    for (int k2 = 0; k2 < 8; ++k2) {
        float bv = -INFINITY;
        int bi = 0x7fffffff;
#pragma unroll
        for (int r = 0; r < 8; ++r) {
            if (!(consumed & (1u << r))) {
                int s = lane + 64 * r;
                float v = vals[r];
                if (v > bv || (v == bv && s < bi)) { bv = v; bi = s; }
            }
        }
#pragma unroll
        for (int off = 1; off < 64; off <<= 1) {
            float ov = __shfl_xor(bv, off, 64);
            int oi = __shfl_xor(bi, off, 64);
            if (ov > bv || (ov == bv && oi < bi)) { bv = ov; bi = oi; }
        }
        if ((bi & 63) == lane) consumed |= 1u << (bi >> 6);
        if (lane == 0) topk[(size_t)bt * 8 + k2] = bi;
    }
}

// ---------------------------------------------------------------------------
// K5: sparse attention (8 compressed + <=16 sliding keys), inverse rope,
// fused gate + output projections. 4 tokens per block (1024 thr),
// 4 waves per token = one per head.
// ---------------------------------------------------------------------------
__global__ __launch_bounds__(1024) void k_attn_out(
    const float* __restrict__ Qr, const float* __restrict__ Kbuf,
    const float* __restrict__ Vbuf, const int* __restrict__ topk,
    const float* __restrict__ Wg0, const float* __restrict__ bg0,
    const float* __restrict__ Wg1, const float* __restrict__ bg1,
    const float* __restrict__ Wout, const float* __restrict__ bout,
    float* __restrict__ out)
{
    int tid = threadIdx.x;
    int lt = tid >> 8;       // local token 0..3
    int t256 = tid & 255;
    int h = t256 >> 6;
    int lane = tid & 63;
    int bt = blockIdx.x * 4 + lt;
    int b = bt >> 11;
    int t = bt & 2047;

    __shared__ float sQ[4][256];
    __shared__ int sPos[4][24];
    __shared__ float sP[4][4][24];
    __shared__ float sO[4][256];
    __shared__ float sPall[4][128];

    sQ[lt][t256] = Qr[(size_t)bt * 256 + t256];
    if (t256 < 8) {
        sPos[lt][t256] = topk[(size_t)bt * 8 + t256];
    } else if (t256 < 24) {
        int rel = t256 - 8;
        int sp = t - rel;
        sPos[lt][t256] = (sp >= 0) ? (TC + sp) : -1;
    }
    __syncthreads();

    // scores: lane j < 24 handles key j for head h
    float scv = -INFINITY;
    if (lane < 24) {
        int pos = sPos[lt][lane];
        if (pos >= 0) {
            const float* kr = Kbuf + ((size_t)b * KV_LEN + pos) * 64;
            const float* qh = &sQ[lt][h * 64];
            float dd = 0.f;
#pragma unroll
            for (int c = 0; c < 64; ++c) dd = fmaf(qh[c], kr[c], dd);
            scv = dd * 0.125f;  // / sqrt(64)
        }
    }
    float m = scv;
#pragma unroll
    for (int off = 1; off < 64; off <<= 1) m = fmaxf(m, __shfl_xor(m, off, 64));
    float p = expf(scv - m);
    if (scv == -INFINITY) p = 0.f;
    float l = p;
#pragma unroll
    for (int off = 1; off < 64; off <<= 1) l += __shfl_xor(l, off, 64);
    p /= l;
    if (lane < 24) sP[lt][h][lane] = p;
    __syncthreads();

    // O_c = sum_j p_j * V[pos_j][c]
    float o = 0.f;
    for (int j2 = 0; j2 < 24; ++j2) {
        int pos = sPos[lt][j2];
        if (pos >= 0) {
            float pj = sP[lt][h][j2];
            o = fmaf(pj, Vbuf[((size_t)b * KV_LEN + pos) * 64 + lane], o);
        }
    }

    // inverse rope at pos t
    int j = lane & 31;
    float sa, ca;
    sincosf(rope_angle(t, j), &sa, &ca);
    float prt = __shfl_xor(o, 32, 64);
    float oo = (lane < 32) ? fmaf(o, ca, prt * sa) : fmaf(-prt, sa, o * ca);
    sO[lt][h * 64 + lane] = oo;   // [0:128]=heads 0,1  [128:256]=heads 2,3
    __syncthreads();

    // p_all = [O01@Wg0+bg0, O23@Wg1+bg1]
    if (t256 < 128) {
        float a;
        if (t256 < 64) {
            a = bg0[t256];
            for (int c = 0; c < 128; ++c) a = fmaf(sO[lt][c], Wg0[c * 64 + t256], a);
        } else {
            int i = t256 - 64;
            a = bg1[i];
            for (int c = 0; c < 128; ++c) a = fmaf(sO[lt][128 + c], Wg1[c * 64 + i], a);
        }
        sPall[lt][t256] = a;
    }
    __syncthreads();

    // out = p_all @ Wout + bout
    float a = bout[t256];
    for (int i = 0; i < 128; ++i) a = fmaf(sPall[lt][i], Wout[i * 256 + t256], a);
    out[(size_t)bt * 256 + t256] = a;
}

// ---------------------------------------------------------------------------
extern "C" void kernel_launch(void* const* d_in, const int* in_sizes, int n_in,
                              void* d_out, int out_size, void* d_ws, size_t ws_size,
                              hipStream_t stream) {
    const float* H       = (const float*)d_in[0];
    const float* Wc_comp = (const float*)d_in[1];
    const float* Wc_idx  = (const float*)d_in[2];
    const float* W_DQ    = (const float*)d_in[3];
    const float* W_IUQ   = (const float*)d_in[4];
    const float* W_w     = (const float*)d_in[5];
    const float* W_Q     = (const float*)d_in[6];
    const float* W_KV    = (const float*)d_in[7];
    const float* g_q     = (const float*)d_in[8];
    const float* g_k     = (const float*)d_in[9];
    const float* g_v     = (const float*)d_in[10];
    const float* Wg0     = (const float*)d_in[11];
    const float* bg0     = (const float*)d_in[12];
    const float* Wg1     = (const float*)d_in[13];
    const float* bg1     = (const float*)d_in[14];
    const float* Wout    = (const float*)d_in[15];
    const float* bout    = (const float*)d_in[16];

    float* ws  = (float*)d_ws;
    float* QI  = ws;                  // B*T*128   = 524288
    float* Qr  = QI + 524288;         // B*T*256   = 1048576
    float* Wiw = Qr + 1048576;        // B*T*4     = 16384
    float* KI  = Wiw + 16384;         // B*TC*32   = 32768
    float* Kb  = KI + 32768;          // B*2560*64 = 327680
    float* Vb  = Kb + 327680;         // B*2560*64 = 327680
    int* topkb = (int*)(Vb + 327680); // B*T*8     = 32768 ints

    float* outp = (float*)d_out;

    hipLaunchKernelGGL(k_pertoken, dim3((B_DIM * T_DIM) / 4), dim3(256), 0, stream,
                       H, W_DQ, W_IUQ, W_w, W_Q, W_KV, g_q, g_k, g_v,
                       QI, Wiw, Qr, Kb, Vb);
    hipLaunchKernelGGL(k_compress, dim3((B_DIM * TC) / 4), dim3(256), 0, stream,
                       H, Wc_comp, Wc_idx, g_k, g_v, KI, Kb, Vb);
    hipLaunchKernelGGL(k_score_topk, dim3((B_DIM * T_DIM) / 4), dim3(256), 0, stream,
                       QI, Wiw, KI, topkb);
    hipLaunchKernelGGL(k_attn_out, dim3((B_DIM * T_DIM) / 4), dim3(1024), 0, stream,
                       Qr, Kb, Vb, topkb, Wg0, bg0, Wg1, bg1, Wout, bout, outp);
}

// Round 2
// 249.497 us; speedup vs baseline: 1.3871x; 1.3871x over previous
//
#include <hip/hip_runtime.h>
#include <math.h>

#define T_DIM 2048
#define B_DIM 2
#define D_DIM 256
#define TC 512
#define KV_LEN 2560   // TC + T

__device__ __forceinline__ float wave_sum64(float v) {
#pragma unroll
    for (int off = 32; off > 0; off >>= 1) v += __shfl_xor(v, off, 64);
    return v;
}

__device__ __forceinline__ float rope_angle(int pos, int j) {
    float inv = powf(10000.0f, -(float)j * (1.0f / 32.0f));
    return (float)pos * inv;
}

// ---------------------------------------------------------------------------
// K1: tiled GEMM  Pre = H @ [W_Q(256) | W_KV(64) | W_DQ(64)]  (384 cols)
// 16 tokens/block, 384 threads, thread tile = 4 tokens x 4 cols.
// Fused epilogue: Q rms+rope -> Qr; KV rms+rope -> Kb/Vb; Hdc@W_IUQ -> QI, W_w -> Wiw.
// ---------------------------------------------------------------------------
__global__ __launch_bounds__(384) void k_proj(
    const float* __restrict__ H, const float* __restrict__ W_Q,
    const float* __restrict__ W_KV, const float* __restrict__ W_DQ,
    const float* __restrict__ W_IUQ, const float* __restrict__ W_w,
    const float* __restrict__ g_q, const float* __restrict__ g_k,
    const float* __restrict__ g_v,
    float* __restrict__ QI, float* __restrict__ Wiw, float* __restrict__ Qr,
    float* __restrict__ Kbuf, float* __restrict__ Vbuf)
{
    int tid = threadIdx.x;
    int bt0 = blockIdx.x * 16;

    __shared__ float sH[16][256];   // 16 KB
    __shared__ float sW[32][384];   // 48 KB (reused as sPre[16][384] later)

    // stage H tile: 16 rows x 256
    for (int i = tid; i < 1024; i += 384) {
        int tok = i >> 6;
        int c4 = (i & 63) << 2;
        *(float4*)&sH[tok][c4] = *(const float4*)(H + ((size_t)(bt0 + tok) << 8) + c4);
    }

    int cg = tid % 96;     // col group -> cols 4*cg..4*cg+3
    int tg = tid / 96;     // token group -> tokens 4*tg..4*tg+3
    int c0 = cg * 4;

    float acc[4][4];
#pragma unroll
    for (int a = 0; a < 4; ++a)
#pragma unroll
        for (int b2 = 0; b2 < 4; ++b2) acc[a][b2] = 0.f;

    for (int kc = 0; kc < 8; ++kc) {
        int i0 = kc * 32;
        __syncthreads();
        // stage W chunk: rows i0..i0+31, 384 cols
        for (int i = tid; i < 3072; i += 384) {
            int r = i / 96;
            int cc = (i % 96) * 4;
            int gr = i0 + r;
            float4 v;
            if (cc < 256)      v = *(const float4*)(W_Q  + (size_t)gr * 256 + cc);
            else if (cc < 320) v = *(const float4*)(W_KV + (size_t)gr * 64 + (cc - 256));
            else               v = *(const float4*)(W_DQ + (size_t)gr * 64 + (cc - 320));
            *(float4*)&sW[r][cc] = v;
        }
        __syncthreads();

        for (int k4 = 0; k4 < 32; k4 += 4) {
            float4 h4[4], w4[4];
#pragma unroll
            for (int tt = 0; tt < 4; ++tt) h4[tt] = *(float4*)&sH[4 * tg + tt][i0 + k4];
#pragma unroll
            for (int kk = 0; kk < 4; ++kk) w4[kk] = *(float4*)&sW[k4 + kk][c0];
#pragma unroll
            for (int kk = 0; kk < 4; ++kk) {
#pragma unroll
                for (int tt = 0; tt < 4; ++tt) {
                    float h = ((const float*)&h4[tt])[kk];
                    acc[tt][0] = fmaf(h, w4[kk].x, acc[tt][0]);
                    acc[tt][1] = fmaf(h, w4[kk].y, acc[tt][1]);
                    acc[tt][2] = fmaf(h, w4[kk].z, acc[tt][2]);
                    acc[tt][3] = fmaf(h, w4[kk].w, acc[tt][3]);
                }
            }
        }
    }

    __syncthreads();
    float (*sPre)[384] = sW;   // reuse
#pragma unroll
    for (int tt = 0; tt < 4; ++tt) {
        float4 v = make_float4(acc[tt][0], acc[tt][1], acc[tt][2], acc[tt][3]);
        *(float4*)&sPre[4 * tg + tt][c0] = v;
    }
    __syncthreads();

    // epilogue: wave per token (6 waves cover 16 tokens)
    int wv = tid >> 6;
    int lane = tid & 63;
    int j = lane & 31;
    for (int tok = wv; tok < 16; tok += 6) {
        int bt = bt0 + tok;
        int b = bt >> 11;
        int t = bt & 2047;

        float s_t, c_t;
        sincosf(rope_angle(t, j), &s_t, &c_t);

        // Q heads: rms per head, g_q, rope(t)
#pragma unroll
        for (int r = 0; r < 4; ++r) {
            float qv = sPre[tok][r * 64 + lane];
            float ss = wave_sum64(qv * qv);
            float sc = rsqrtf(ss * (1.0f / 64.0f) + 1e-6f);
            float q = qv * sc * g_q[r * 64 + lane];
            float prt = __shfl_xor(q, 32, 64);
            float o = (lane < 32) ? fmaf(q, c_t, -prt * s_t)
                                  : fmaf(prt, s_t, q * c_t);
            Qr[(size_t)bt * 256 + r * 64 + lane] = o;
        }

        // sliding KV: rms, g_k/g_v, rope at pos TC+t
        {
            float kvv = sPre[tok][256 + lane];
            float ss = wave_sum64(kvv * kvv);
            float sc = rsqrtf(ss * (1.0f / 64.0f) + 1e-6f);
            float kk = kvv * sc * g_k[lane];
            float vv = kvv * sc * g_v[lane];
            int pos = TC + t;
            float s_p, c_p;
            sincosf(rope_angle(pos, j), &s_p, &c_p);
            float pk = __shfl_xor(kk, 32, 64);
            float pv = __shfl_xor(vv, 32, 64);
            float ko = (lane < 32) ? fmaf(kk, c_p, -pk * s_p) : fmaf(pk, s_p, kk * c_p);
            float vo = (lane < 32) ? fmaf(vv, c_p, -pv * s_p) : fmaf(pv, s_p, vv * c_p);
            size_t off = ((size_t)b * KV_LEN + pos) * 64 + lane;
            Kbuf[off] = ko;
            Vbuf[off] = vo;
        }

        // QI = Hdc @ W_IUQ (128 cols, 2 per lane); Wiw = Hdc @ W_w
        {
            float a0 = 0.f, a1 = 0.f;
#pragma unroll 8
            for (int jj = 0; jj < 64; ++jj) {
                float hv = sPre[tok][320 + jj];
                a0 = fmaf(hv, W_IUQ[jj * 128 + lane], a0);
                a1 = fmaf(hv, W_IUQ[jj * 128 + 64 + lane], a1);
            }
            QI[(size_t)bt * 128 + lane] = a0;
            QI[(size_t)bt * 128 + 64 + lane] = a1;
            if (lane < 4) {
                float aw = 0.f;
                for (int jj = 0; jj < 64; ++jj)
                    aw = fmaf(sPre[tok][320 + jj], W_w[jj * 4 + lane], aw);
                Wiw[(size_t)bt * 4 + lane] = aw;
            }
        }
    }
}

// ---------------------------------------------------------------------------
// K2: compress GEMM, split-K. 2 compressed tokens/block, 4 waves each own a
// 512-wide K chunk; LDS reduce; rms+rope epilogue. Grid = B*TC/2 = 512.
// ---------------------------------------------------------------------------
__global__ __launch_bounds__(256) void k_compress(
    const float* __restrict__ H, const float* __restrict__ Wc_comp,
    const float* __restrict__ Wc_idx, const float* __restrict__ g_k,
    const float* __restrict__ g_v,
    float* __restrict__ KIbuf, float* __restrict__ Kbuf, float* __restrict__ Vbuf)
{
    int tid = threadIdx.x;
    int wv = tid >> 6;
    int lane = tid & 63;
    int bid = blockIdx.x;
    int b = bid >> 8;
    int s0 = (bid & 255) * 2;

    __shared__ float sA[2][4][512];      // 16 KB
    __shared__ float sRed[4][2][64];
    __shared__ float sRedI[4][2][32];

    // stage A rows for this wave's K chunk: token tt needs H rows 4(s0+tt)+2wv+{0,1}
#pragma unroll
    for (int tt = 0; tt < 2; ++tt) {
#pragma unroll
        for (int rl = 0; rl < 2; ++rl) {
            int row = 4 * (s0 + tt) + 2 * wv + rl;
            float4 v = make_float4(0.f, 0.f, 0.f, 0.f);
            if (row < T_DIM)
                v = *(const float4*)(H + ((size_t)b * T_DIM + row) * 256 + lane * 4);
            *(float4*)&sA[tt][wv][rl * 256 + lane * 4] = v;
        }
    }
    // each wave reads only its own slice -> no cross-wave sync needed here

    int k0 = wv * 512;

    // KVc partial (64 cols, lane=col), 2 tokens
    float ac0 = 0.f, ac1 = 0.f;
    const float* Wc = Wc_comp + (size_t)k0 * 64 + lane;
    for (int k = 0; k < 512; k += 4) {
        float4 a0 = *(float4*)&sA[0][wv][k];
        float4 a1 = *(float4*)&sA[1][wv][k];
#pragma unroll
        for (int kk = 0; kk < 4; ++kk) {
            float w = Wc[(size_t)(k + kk) * 64];
            ac0 = fmaf(((const float*)&a0)[kk], w, ac0);
            ac1 = fmaf(((const float*)&a1)[kk], w, ac1);
        }
    }
    sRed[wv][0][lane] = ac0;
    sRed[wv][1][lane] = ac1;

    // K_I partial (32 cols): half-waves split the 512 chunk
    {
        int col = lane & 31;
        int half = lane >> 5;
        float ai0 = 0.f, ai1 = 0.f;
        const float* Wi = Wc_idx + (size_t)k0 * 32 + col;
        int kb = half * 256;
        for (int k = kb; k < kb + 256; k += 4) {
            float4 a0 = *(float4*)&sA[0][wv][k];
            float4 a1 = *(float4*)&sA[1][wv][k];
#pragma unroll
            for (int kk = 0; kk < 4; ++kk) {
                float w = Wi[(size_t)(k + kk) * 32];
                ai0 = fmaf(((const float*)&a0)[kk], w, ai0);
                ai1 = fmaf(((const float*)&a1)[kk], w, ai1);
            }
        }
        ai0 += __shfl_xor(ai0, 32, 64);
        ai1 += __shfl_xor(ai1, 32, 64);
        if (lane < 32) {
            sRedI[wv][0][lane] = ai0;
            sRedI[wv][1][lane] = ai1;
        }
    }
    __syncthreads();

    if (wv < 2) {
        // KVc reduce + rms + rope for token tt = wv
        int tt = wv;
        int s = s0 + tt;
        float kvv = sRed[0][tt][lane] + sRed[1][tt][lane] + sRed[2][tt][lane] + sRed[3][tt][lane];
        float ss = wave_sum64(kvv * kvv);
        float sc = rsqrtf(ss * (1.0f / 64.0f) + 1e-6f);
        float kk = kvv * sc * g_k[lane];
        float vv = kvv * sc * g_v[lane];
        int j = lane & 31;
        float sa, ca;
        sincosf(rope_angle(s, j), &sa, &ca);
        float pk = __shfl_xor(kk, 32, 64);
        float pv = __shfl_xor(vv, 32, 64);
        float ko = (lane < 32) ? fmaf(kk, ca, -pk * sa) : fmaf(pk, sa, kk * ca);
        float vo = (lane < 32) ? fmaf(vv, ca, -pv * sa) : fmaf(pv, sa, vv * ca);
        size_t off = ((size_t)b * KV_LEN + s) * 64 + lane;
        Kbuf[off] = ko;
        Vbuf[off] = vo;
    } else {
        // K_I reduce for token tt = wv-2
        int tt = wv - 2;
        int s = s0 + tt;
        if (lane < 32) {
            float a = sRedI[0][tt][lane] + sRedI[1][tt][lane] + sRedI[2][tt][lane] + sRedI[3][tt][lane];
            KIbuf[((size_t)b * TC + s) * 32 + lane] = a;
        }
    }
}

// ---------------------------------------------------------------------------
// K3: index scores I_ts + exact top-8 (value desc, index asc; -inf selectable)
// 4 tokens per block, wave per token; lane holds 8 s-slots.
// ---------------------------------------------------------------------------
__global__ __launch_bounds__(256) void k_score_topk(
    const float* __restrict__ QI, const float* __restrict__ Wiw,
    const float* __restrict__ KIbuf, int* __restrict__ topk)
{
    int wv = threadIdx.x >> 6;
    int lane = threadIdx.x & 63;
    int bt = blockIdx.x * 4 + wv;
    int b = bt >> 11;
    int t = bt & 2047;

    __shared__ float sQ[4][128];
    __shared__ float sw[4][4];
    sQ[wv][lane] = QI[(size_t)bt * 128 + lane];
    sQ[wv][64 + lane] = QI[(size_t)bt * 128 + 64 + lane];
    if (lane < 4) sw[wv][lane] = Wiw[(size_t)bt * 4 + lane];
    __syncthreads();

    const float* KIb = KIbuf + (size_t)b * TC * 32;
    int smax = t >> 2;
    float vals[8];
#pragma unroll
    for (int r = 0; r < 8; ++r) {
        int s = lane + 64 * r;
        float v = -INFINITY;
        if (s <= smax) {
            float4 kr[8];
            const float4* krp = (const float4*)(KIb + s * 32);
#pragma unroll
            for (int c4 = 0; c4 < 8; ++c4) kr[c4] = krp[c4];
            float acc = 0.f;
#pragma unroll
            for (int h2 = 0; h2 < 4; ++h2) {
                float dd = 0.f;
#pragma unroll
                for (int c4 = 0; c4 < 8; ++c4) {
                    float4 q4 = *(const float4*)&sQ[wv][h2 * 32 + c4 * 4];
                    dd = fmaf(q4.x, kr[c4].x, dd);
                    dd = fmaf(q4.y, kr[c4].y, dd);
                    dd = fmaf(q4.z, kr[c4].z, dd);
                    dd = fmaf(q4.w, kr[c4].w, dd);
                }
                acc = fmaf(sw[wv][h2], fmaxf(dd, 0.f), acc);
            }
            v = acc;
        }
        vals[r] = v;
    }

    unsigned consumed = 0u;
    for (int k2 = 0; k2 < 8; ++k2) {
        float bv = -INFINITY;
        int bi = 0x7fffffff;
#pragma unroll
        for (int r = 0; r < 8; ++r) {
            if (!(consumed & (1u << r))) {
                int s = lane + 64 * r;
                float v = vals[r];
                if (v > bv || (v == bv && s < bi)) { bv = v; bi = s; }
            }
        }
#pragma unroll
        for (int off = 1; off < 64; off <<= 1) {
            float ov = __shfl_xor(bv, off, 64);
            int oi = __shfl_xor(bi, off, 64);
            if (ov > bv || (ov == bv && oi < bi)) { bv = ov; bi = oi; }
        }
        if ((bi & 63) == lane) consumed |= 1u << (bi >> 6);
        if (lane == 0) topk[(size_t)bt * 8 + k2] = bi;
    }
}

// ---------------------------------------------------------------------------
// K4: sparse attention (8 compressed + <=16 sliding keys), inverse rope,
// fused gate + output projections. 4 tokens/block (1024 thr), wave per head.
// ---------------------------------------------------------------------------
__global__ __launch_bounds__(1024) void k_attn_out(
    const float* __restrict__ Qr, const float* __restrict__ Kbuf,
    const float* __restrict__ Vbuf, const int* __restrict__ topk,
    const float* __restrict__ Wg0, const float* __restrict__ bg0,
    const float* __restrict__ Wg1, const float* __restrict__ bg1,
    const float* __restrict__ Wout, const float* __restrict__ bout,
    float* __restrict__ out)
{
    int tid = threadIdx.x;
    int lt = tid >> 8;
    int t256 = tid & 255;
    int h = t256 >> 6;
    int lane = tid & 63;
    int bt = blockIdx.x * 4 + lt;
    int b = bt >> 11;
    int t = bt & 2047;

    __shared__ float sQ[4][256];
    __shared__ int sPos[4][24];
    __shared__ float sP[4][4][24];
    __shared__ float sO[4][256];
    __shared__ float sPall[4][128];

    sQ[lt][t256] = Qr[(size_t)bt * 256 + t256];
    if (t256 < 8) {
        sPos[lt][t256] = topk[(size_t)bt * 8 + t256];
    } else if (t256 < 24) {
        int rel = t256 - 8;
        int sp = t - rel;
        sPos[lt][t256] = (sp >= 0) ? (TC + sp) : -1;
    }
    __syncthreads();

    float scv = -INFINITY;
    if (lane < 24) {
        int pos = sPos[lt][lane];
        if (pos >= 0) {
            const float4* kr = (const float4*)(Kbuf + ((size_t)b * KV_LEN + pos) * 64);
            const float4* qh = (const float4*)&sQ[lt][h * 64];
            float dd = 0.f;
#pragma unroll
            for (int c4 = 0; c4 < 16; ++c4) {
                float4 q4 = qh[c4];
                float4 k4 = kr[c4];
                dd = fmaf(q4.x, k4.x, dd);
                dd = fmaf(q4.y, k4.y, dd);
                dd = fmaf(q4.z, k4.z, dd);
                dd = fmaf(q4.w, k4.w, dd);
            }
            scv = dd * 0.125f;
        }
    }
    float m = scv;
#pragma unroll
    for (int off = 1; off < 64; off <<= 1) m = fmaxf(m, __shfl_xor(m, off, 64));
    float p = expf(scv - m);
    if (scv == -INFINITY) p = 0.f;
    float l = p;
#pragma unroll
    for (int off = 1; off < 64; off <<= 1) l += __shfl_xor(l, off, 64);
    p /= l;
    if (lane < 24) sP[lt][h][lane] = p;
    __syncthreads();

    float o = 0.f;
    for (int j2 = 0; j2 < 24; ++j2) {
        int pos = sPos[lt][j2];
        if (pos >= 0) {
            float pj = sP[lt][h][j2];
            o = fmaf(pj, Vbuf[((size_t)b * KV_LEN + pos) * 64 + lane], o);
        }
    }

    int j = lane & 31;
    float sa, ca;
    sincosf(rope_angle(t, j), &sa, &ca);
    float prt = __shfl_xor(o, 32, 64);
    float oo = (lane < 32) ? fmaf(o, ca, prt * sa) : fmaf(-prt, sa, o * ca);
    sO[lt][h * 64 + lane] = oo;
    __syncthreads();

    if (t256 < 128) {
        float a;
        if (t256 < 64) {
            a = bg0[t256];
            for (int c = 0; c < 128; ++c) a = fmaf(sO[lt][c], Wg0[c * 64 + t256], a);
        } else {
            int i = t256 - 64;
            a = bg1[i];
            for (int c = 0; c < 128; ++c) a = fmaf(sO[lt][128 + c], Wg1[c * 64 + i], a);
        }
        sPall[lt][t256] = a;
    }
    __syncthreads();

    float a = bout[t256];
    for (int i = 0; i < 128; ++i) a = fmaf(sPall[lt][i], Wout[i * 256 + t256], a);
    out[(size_t)bt * 256 + t256] = a;
}

// ---------------------------------------------------------------------------
extern "C" void kernel_launch(void* const* d_in, const int* in_sizes, int n_in,
                              void* d_out, int out_size, void* d_ws, size_t ws_size,
                              hipStream_t stream) {
    const float* H       = (const float*)d_in[0];
    const float* Wc_comp = (const float*)d_in[1];
    const float* Wc_idx  = (const float*)d_in[2];
    const float* W_DQ    = (const float*)d_in[3];
    const float* W_IUQ   = (const float*)d_in[4];
    const float* W_w     = (const float*)d_in[5];
    const float* W_Q     = (const float*)d_in[6];
    const float* W_KV    = (const float*)d_in[7];
    const float* g_q     = (const float*)d_in[8];
    const float* g_k     = (const float*)d_in[9];
    const float* g_v     = (const float*)d_in[10];
    const float* Wg0     = (const float*)d_in[11];
    const float* bg0     = (const float*)d_in[12];
    const float* Wg1     = (const float*)d_in[13];
    const float* bg1     = (const float*)d_in[14];
    const float* Wout    = (const float*)d_in[15];
    const float* bout    = (const float*)d_in[16];

    float* ws  = (float*)d_ws;
    float* QI  = ws;                  // B*T*128   = 524288
    float* Qr  = QI + 524288;         // B*T*256   = 1048576
    float* Wiw = Qr + 1048576;        // B*T*4     = 16384
    float* KI  = Wiw + 16384;         // B*TC*32   = 32768
    float* Kb  = KI + 32768;          // B*2560*64 = 327680
    float* Vb  = Kb + 327680;         // B*2560*64 = 327680
    int* topkb = (int*)(Vb + 327680); // B*T*8

    float* outp = (float*)d_out;

    hipLaunchKernelGGL(k_compress, dim3((B_DIM * TC) / 2), dim3(256), 0, stream,
                       H, Wc_comp, Wc_idx, g_k, g_v, KI, Kb, Vb);
    hipLaunchKernelGGL(k_proj, dim3((B_DIM * T_DIM) / 16), dim3(384), 0, stream,
                       H, W_Q, W_KV, W_DQ, W_IUQ, W_w, g_q, g_k, g_v,
                       QI, Wiw, Qr, Kb, Vb);
    hipLaunchKernelGGL(k_score_topk, dim3((B_DIM * T_DIM) / 4), dim3(256), 0, stream,
                       QI, Wiw, KI, topkb);
    hipLaunchKernelGGL(k_attn_out, dim3((B_DIM * T_DIM) / 4), dim3(1024), 0, stream,
                       Qr, Kb, Vb, topkb, Wg0, bg0, Wg1, bg1, Wout, bout, outp);
}

// Round 3
// 213.150 us; speedup vs baseline: 1.6236x; 1.1705x over previous
//
#include <hip/hip_runtime.h>
#include <math.h>

#define T_DIM 2048
#define B_DIM 2
#define D_DIM 256
#define TC 512
#define KV_LEN 2560   // TC + T

__device__ __forceinline__ float wave_sum64(float v) {
#pragma unroll
    for (int off = 32; off > 0; off >>= 1) v += __shfl_xor(v, off, 64);
    return v;
}

__device__ __forceinline__ float rope_angle(int pos, int j) {
    float inv = powf(10000.0f, -(float)j * (1.0f / 32.0f));
    return (float)pos * inv;
}

// ---------------------------------------------------------------------------
// Phase 1 (fused): blocks [0,512) = proj, [512,1024) = compress. 256 threads.
//
// proj: Pre = H @ [W_Q | W_KV | W_DQ] for 8 tokens/block. Wave tg owns tokens
// {2tg, 2tg+1}; lane cg owns cols {cg + 64m}. acc[tt][m]: m=0..3 -> Q head m
// (lane = col within head), m=4 -> KV col lane, m=5 -> H_dc col lane. So the
// RMS/rope epilogue is wave-local with zero LDS round-trip.
// ---------------------------------------------------------------------------
__global__ __launch_bounds__(256) void k_phase1(
    const float* __restrict__ H, const float* __restrict__ W_Q,
    const float* __restrict__ W_KV, const float* __restrict__ W_DQ,
    const float* __restrict__ W_IUQ, const float* __restrict__ W_w,
    const float* __restrict__ Wc_comp, const float* __restrict__ Wc_idx,
    const float* __restrict__ g_q, const float* __restrict__ g_k,
    const float* __restrict__ g_v,
    float* __restrict__ QI, float* __restrict__ Wiw, float* __restrict__ Qr,
    float* __restrict__ KIbuf, float* __restrict__ Kbuf, float* __restrict__ Vbuf)
{
    __shared__ float smem[8960];   // 35 KB
    int tid = threadIdx.x;
    int lane = tid & 63;

    if (blockIdx.x < 512) {
        // ---------------- proj path ----------------
        int bt0 = blockIdx.x * 8;
        float* sH = smem;            // 8*256 = 2048
        float* sW = smem + 2048;     // 16*384 = 6144
        float* sHdc = smem + 8192;   // 8*64 = 512
        float* sWw = smem + 8704;    // 64*4 = 256
        // sWI reuses smem[0..8191] after GEMM

        for (int i = tid; i < 512; i += 256) {
            int tok = i >> 6;
            int c4 = (i & 63) << 2;
            *(float4*)&sH[tok * 256 + c4] =
                *(const float4*)(H + ((size_t)(bt0 + tok) << 8) + c4);
        }

        int cg = lane;
        int tg = tid >> 6;
        float acc[2][6];
#pragma unroll
        for (int a = 0; a < 2; ++a)
#pragma unroll
            for (int m = 0; m < 6; ++m) acc[a][m] = 0.f;

        for (int kc = 0; kc < 16; ++kc) {
            __syncthreads();
            for (int i = tid; i < 1536; i += 256) {
                int r = i / 96;
                int cc = (i % 96) * 4;
                int gr = kc * 16 + r;
                float4 v;
                if (cc < 256)      v = *(const float4*)(W_Q + (size_t)gr * 256 + cc);
                else if (cc < 320) v = *(const float4*)(W_KV + (size_t)gr * 64 + (cc - 256));
                else               v = *(const float4*)(W_DQ + (size_t)gr * 64 + (cc - 320));
                *(float4*)&sW[r * 384 + cc] = v;
            }
            __syncthreads();
#pragma unroll
            for (int k = 0; k < 16; ++k) {
                float h0 = sH[(2 * tg) * 256 + kc * 16 + k];
                float h1 = sH[(2 * tg + 1) * 256 + kc * 16 + k];
#pragma unroll
                for (int m = 0; m < 6; ++m) {
                    float w = sW[k * 384 + cg + 64 * m];
                    acc[0][m] = fmaf(h0, w, acc[0][m]);
                    acc[1][m] = fmaf(h1, w, acc[1][m]);
                }
            }
        }

        // park H_dc, then overwrite sH/sW with W_IUQ (+ W_w)
#pragma unroll
        for (int tt = 0; tt < 2; ++tt)
            sHdc[(2 * tg + tt) * 64 + lane] = acc[tt][5];
        __syncthreads();
        for (int i = tid * 4; i < 8192; i += 1024)
            *(float4*)&smem[i] = *(const float4*)(W_IUQ + i);
        if (tid < 64) ((float4*)sWw)[tid] = ((const float4*)W_w)[tid];
        __syncthreads();
        float* sWI = smem;

        int j = lane & 31;
#pragma unroll
        for (int tt = 0; tt < 2; ++tt) {
            int tok = 2 * tg + tt;
            int bt = bt0 + tok;
            int b = bt >> 11;
            int t = bt & 2047;

            float s_t, c_t;
            sincosf(rope_angle(t, j), &s_t, &c_t);

#pragma unroll
            for (int r = 0; r < 4; ++r) {
                float qv = acc[tt][r];
                float ss = wave_sum64(qv * qv);
                float sc = rsqrtf(ss * (1.0f / 64.0f) + 1e-6f);
                float q = qv * sc * g_q[r * 64 + lane];
                float prt = __shfl_xor(q, 32, 64);
                float o = (lane < 32) ? fmaf(q, c_t, -prt * s_t)
                                      : fmaf(prt, s_t, q * c_t);
                Qr[(size_t)bt * 256 + r * 64 + lane] = o;
            }
            {
                float kvv = acc[tt][4];
                float ss = wave_sum64(kvv * kvv);
                float sc = rsqrtf(ss * (1.0f / 64.0f) + 1e-6f);
                float kk = kvv * sc * g_k[lane];
                float vv = kvv * sc * g_v[lane];
                int pos = TC + t;
                float s_p, c_p;
                sincosf(rope_angle(pos, j), &s_p, &c_p);
                float pk = __shfl_xor(kk, 32, 64);
                float pv = __shfl_xor(vv, 32, 64);
                float ko = (lane < 32) ? fmaf(kk, c_p, -pk * s_p) : fmaf(pk, s_p, kk * c_p);
                float vo = (lane < 32) ? fmaf(vv, c_p, -pv * s_p) : fmaf(pv, s_p, vv * c_p);
                size_t off = ((size_t)b * KV_LEN + pos) * 64 + lane;
                Kbuf[off] = ko;
                Vbuf[off] = vo;
            }
            {
                float a0 = 0.f, a1 = 0.f;
#pragma unroll 8
                for (int jj = 0; jj < 64; ++jj) {
                    float hv = sHdc[tok * 64 + jj];
                    a0 = fmaf(hv, sWI[jj * 128 + lane], a0);
                    a1 = fmaf(hv, sWI[jj * 128 + 64 + lane], a1);
                }
                QI[(size_t)bt * 128 + lane] = a0;
                QI[(size_t)bt * 128 + 64 + lane] = a1;
                if (lane < 4) {
                    float aw = 0.f;
                    for (int jj = 0; jj < 64; ++jj)
                        aw = fmaf(sHdc[tok * 64 + jj], sWw[jj * 4 + lane], aw);
                    Wiw[(size_t)bt * 4 + lane] = aw;
                }
            }
        }
    } else {
        // ---------------- compress path ----------------
        int cid = blockIdx.x - 512;
        int wv = tid >> 6;
        int b = cid >> 8;
        int s0 = (cid & 255) * 2;

        float* sA = smem;            // [tt*4+wv][512] : 4096
        float* sRed = smem + 4096;   // [wv*2+tt][64]  : 512
        float* sRedI = smem + 4608;  // [wv*2+tt][32]  : 128

#pragma unroll
        for (int tt = 0; tt < 2; ++tt) {
#pragma unroll
            for (int rl = 0; rl < 2; ++rl) {
                int row = 4 * (s0 + tt) + 2 * wv + rl;
                float4 v = make_float4(0.f, 0.f, 0.f, 0.f);
                if (row < T_DIM)
                    v = *(const float4*)(H + ((size_t)b * T_DIM + row) * 256 + lane * 4);
                *(float4*)&sA[(tt * 4 + wv) * 512 + rl * 256 + lane * 4] = v;
            }
        }

        int k0 = wv * 512;
        float ac0 = 0.f, ac1 = 0.f;
        const float* Wc = Wc_comp + (size_t)k0 * 64 + lane;
        for (int k = 0; k < 512; k += 4) {
            float4 a0 = *(float4*)&sA[(0 * 4 + wv) * 512 + k];
            float4 a1 = *(float4*)&sA[(1 * 4 + wv) * 512 + k];
#pragma unroll
            for (int kk = 0; kk < 4; ++kk) {
                float w = Wc[(size_t)(k + kk) * 64];
                ac0 = fmaf(((const float*)&a0)[kk], w, ac0);
                ac1 = fmaf(((const float*)&a1)[kk], w, ac1);
            }
        }
        sRed[(wv * 2 + 0) * 64 + lane] = ac0;
        sRed[(wv * 2 + 1) * 64 + lane] = ac1;

        {
            int col = lane & 31;
            int half = lane >> 5;
            float ai0 = 0.f, ai1 = 0.f;
            const float* Wi = Wc_idx + (size_t)k0 * 32 + col;
            int kb = half * 256;
            for (int k = kb; k < kb + 256; k += 4) {
                float4 a0 = *(float4*)&sA[(0 * 4 + wv) * 512 + k];
                float4 a1 = *(float4*)&sA[(1 * 4 + wv) * 512 + k];
#pragma unroll
                for (int kk = 0; kk < 4; ++kk) {
                    float w = Wi[(size_t)(k + kk) * 32];
                    ai0 = fmaf(((const float*)&a0)[kk], w, ai0);
                    ai1 = fmaf(((const float*)&a1)[kk], w, ai1);
                }
            }
            ai0 += __shfl_xor(ai0, 32, 64);
            ai1 += __shfl_xor(ai1, 32, 64);
            if (lane < 32) {
                sRedI[(wv * 2 + 0) * 32 + lane] = ai0;
                sRedI[(wv * 2 + 1) * 32 + lane] = ai1;
            }
        }
        __syncthreads();

        if (wv < 2) {
            int tt = wv;
            int s = s0 + tt;
            float kvv = sRed[(0 * 2 + tt) * 64 + lane] + sRed[(1 * 2 + tt) * 64 + lane] +
                        sRed[(2 * 2 + tt) * 64 + lane] + sRed[(3 * 2 + tt) * 64 + lane];
            float ss = wave_sum64(kvv * kvv);
            float sc = rsqrtf(ss * (1.0f / 64.0f) + 1e-6f);
            float kk = kvv * sc * g_k[lane];
            float vv = kvv * sc * g_v[lane];
            int j = lane & 31;
            float sa, ca;
            sincosf(rope_angle(s, j), &sa, &ca);
            float pk = __shfl_xor(kk, 32, 64);
            float pv = __shfl_xor(vv, 32, 64);
            float ko = (lane < 32) ? fmaf(kk, ca, -pk * sa) : fmaf(pk, sa, kk * ca);
            float vo = (lane < 32) ? fmaf(vv, ca, -pv * sa) : fmaf(pv, sa, vv * ca);
            size_t off = ((size_t)b * KV_LEN + s) * 64 + lane;
            Kbuf[off] = ko;
            Vbuf[off] = vo;
        } else {
            int tt = wv - 2;
            int s = s0 + tt;
            if (lane < 32) {
                float a = sRedI[(0 * 2 + tt) * 32 + lane] + sRedI[(1 * 2 + tt) * 32 + lane] +
                          sRedI[(2 * 2 + tt) * 32 + lane] + sRedI[(3 * 2 + tt) * 32 + lane];
                KIbuf[((size_t)b * TC + s) * 32 + lane] = a;
            }
        }
    }
}

// ---------------------------------------------------------------------------
// K3: index scores + exact top-8. 4 tokens/block (wave each). KI staged to
// LDS in 64-row chunks (coalesced, pad 33 -> conflict-free), chunks past the
// block's smax skipped (uniform branch).
// ---------------------------------------------------------------------------
__global__ __launch_bounds__(256) void k_score_topk(
    const float* __restrict__ QI, const float* __restrict__ Wiw,
    const float* __restrict__ KIbuf, int* __restrict__ topk)
{
    int tid = threadIdx.x;
    int wv = tid >> 6;
    int lane = tid & 63;
    int bt0 = blockIdx.x * 4;
    int bt = bt0 + wv;
    int b = bt >> 11;
    int t = bt & 2047;

    __shared__ float sQ[4][128];
    __shared__ float sw[4][4];
    __shared__ float sKI[64 * 33];

    sQ[wv][lane] = QI[(size_t)bt * 128 + lane];
    sQ[wv][64 + lane] = QI[(size_t)bt * 128 + 64 + lane];
    if (lane < 4) sw[wv][lane] = Wiw[(size_t)bt * 4 + lane];
    // sQ/sw are wave-local (each wave reads only its own row) -> no barrier.

    const float* KIb = KIbuf + (size_t)b * TC * 32;
    int smax = t >> 2;
    int smax_blk = ((bt0 + 3) & 2047) >> 2;   // block-uniform

    float vals[8];
#pragma unroll
    for (int r = 0; r < 8; ++r) vals[r] = -INFINITY;

    for (int r = 0; r < 8; ++r) {
        if (r * 64 > smax_blk) break;   // uniform
        __syncthreads();
        for (int i = tid; i < 512; i += 256) {
            int row = i >> 3;
            int cseg = (i & 7) * 4;
            float4 v = *(const float4*)(KIb + (size_t)(r * 64 + row) * 32 + cseg);
            float* dst = &sKI[row * 33 + cseg];
            dst[0] = v.x; dst[1] = v.y; dst[2] = v.z; dst[3] = v.w;
        }
        __syncthreads();

        int s = r * 64 + lane;
        if (s <= smax) {
            float dd0 = 0.f, dd1 = 0.f, dd2 = 0.f, dd3 = 0.f;
#pragma unroll
            for (int c = 0; c < 32; ++c) {
                float kv = sKI[lane * 33 + c];
                dd0 = fmaf(sQ[wv][c], kv, dd0);
                dd1 = fmaf(sQ[wv][32 + c], kv, dd1);
                dd2 = fmaf(sQ[wv][64 + c], kv, dd2);
                dd3 = fmaf(sQ[wv][96 + c], kv, dd3);
            }
            vals[r] = sw[wv][0] * fmaxf(dd0, 0.f) + sw[wv][1] * fmaxf(dd1, 0.f) +
                      sw[wv][2] * fmaxf(dd2, 0.f) + sw[wv][3] * fmaxf(dd3, 0.f);
        }
    }

    unsigned consumed = 0u;
    for (int k2 = 0; k2 < 8; ++k2) {
        float bv = -INFINITY;
        int bi = 0x7fffffff;
#pragma unroll
        for (int r = 0; r < 8; ++r) {
            if (!(consumed & (1u << r))) {
                int s = lane + 64 * r;
                float v = vals[r];
                if (v > bv || (v == bv && s < bi)) { bv = v; bi = s; }
            }
        }
#pragma unroll
        for (int off = 1; off < 64; off <<= 1) {
            float ov = __shfl_xor(bv, off, 64);
            int oi = __shfl_xor(bi, off, 64);
            if (ov > bv || (ov == bv && oi < bi)) { bv = ov; bi = oi; }
        }
        if ((bi & 63) == lane) consumed |= 1u << (bi >> 6);
        if (lane == 0) topk[(size_t)bt * 8 + k2] = bi;
    }
}

// ---------------------------------------------------------------------------
// K4: sparse attention + gates + out. 4 tokens/block (1024 thr, wave/head).
// K and V rows staged once per token into LDS (coalesced, pad 65).
// ---------------------------------------------------------------------------
__global__ __launch_bounds__(1024) void k_attn_out(
    const float* __restrict__ Qr, const float* __restrict__ Kbuf,
    const float* __restrict__ Vbuf, const int* __restrict__ topk,
    const float* __restrict__ Wg0, const float* __restrict__ bg0,
    const float* __restrict__ Wg1, const float* __restrict__ bg1,
    const float* __restrict__ Wout, const float* __restrict__ bout,
    float* __restrict__ out)
{
    int tid = threadIdx.x;
    int lt = tid >> 8;
    int t256 = tid & 255;
    int h = t256 >> 6;
    int lane = tid & 63;
    int bt = blockIdx.x * 4 + lt;
    int b = bt >> 11;
    int t = bt & 2047;

    __shared__ float sKV[4][48 * 65];   // rows 0..23 = K, 24..47 = V
    __shared__ float sQ[4][256];
    __shared__ int sPos[4][24];
    __shared__ float sP[4][4][24];
    __shared__ float sO[4][256];
    __shared__ float sPall[4][128];

    sQ[lt][t256] = Qr[(size_t)bt * 256 + t256];
    if (t256 < 8) {
        sPos[lt][t256] = topk[(size_t)bt * 8 + t256];
    } else if (t256 < 24) {
        int rel = t256 - 8;
        int sp = t - rel;
        sPos[lt][t256] = (sp >= 0) ? (TC + sp) : -1;
    }
    __syncthreads();

    // stage K/V rows: 48 rows x 16 float4 per token, 3 float4 per thread
    for (int i = t256; i < 768; i += 256) {
        int row = i >> 4;
        int seg = (i & 15) << 2;
        int key = (row < 24) ? row : row - 24;
        int pos = sPos[lt][key];
        if (pos >= 0) {
            const float* src = ((row < 24) ? Kbuf : Vbuf) +
                               ((size_t)b * KV_LEN + pos) * 64 + seg;
            float4 v = *(const float4*)src;
            float* dst = &sKV[lt][row * 65 + seg];
            dst[0] = v.x; dst[1] = v.y; dst[2] = v.z; dst[3] = v.w;
        }
    }
    __syncthreads();

    // scores (lane j < 24): conflict-free LDS reads
    float scv = -INFINITY;
    if (lane < 24) {
        int pos = sPos[lt][lane];
        if (pos >= 0) {
            float dd = 0.f;
#pragma unroll
            for (int c = 0; c < 64; ++c)
                dd = fmaf(sQ[lt][h * 64 + c], sKV[lt][lane * 65 + c], dd);
            scv = dd * 0.125f;
        }
    }
    float m = scv;
#pragma unroll
    for (int off = 1; off < 64; off <<= 1) m = fmaxf(m, __shfl_xor(m, off, 64));
    float p = expf(scv - m);
    if (scv == -INFINITY) p = 0.f;
    float l = p;
#pragma unroll
    for (int off = 1; off < 64; off <<= 1) l += __shfl_xor(l, off, 64);
    p /= l;
    if (lane < 24) sP[lt][h][lane] = p;   // wave-local: no barrier needed

    float o = 0.f;
#pragma unroll
    for (int j2 = 0; j2 < 24; ++j2) {
        int pos = sPos[lt][j2];
        if (pos >= 0)
            o = fmaf(sP[lt][h][j2], sKV[lt][(24 + j2) * 65 + lane], o);
    }

    int j = lane & 31;
    float sa, ca;
    sincosf(rope_angle(t, j), &sa, &ca);
    float prt = __shfl_xor(o, 32, 64);
    float oo = (lane < 32) ? fmaf(o, ca, prt * sa) : fmaf(-prt, sa, o * ca);
    sO[lt][h * 64 + lane] = oo;
    __syncthreads();

    if (t256 < 128) {
        float a;
        if (t256 < 64) {
            a = bg0[t256];
            for (int c = 0; c < 128; ++c) a = fmaf(sO[lt][c], Wg0[c * 64 + t256], a);
        } else {
            int i = t256 - 64;
            a = bg1[i];
            for (int c = 0; c < 128; ++c) a = fmaf(sO[lt][128 + c], Wg1[c * 64 + i], a);
        }
        sPall[lt][t256] = a;
    }
    __syncthreads();

    float a = bout[t256];
    for (int i = 0; i < 128; ++i) a = fmaf(sPall[lt][i], Wout[i * 256 + t256], a);
    out[(size_t)bt * 256 + t256] = a;
}

// ---------------------------------------------------------------------------
extern "C" void kernel_launch(void* const* d_in, const int* in_sizes, int n_in,
                              void* d_out, int out_size, void* d_ws, size_t ws_size,
                              hipStream_t stream) {
    const float* H       = (const float*)d_in[0];
    const float* Wc_comp = (const float*)d_in[1];
    const float* Wc_idx  = (const float*)d_in[2];
    const float* W_DQ    = (const float*)d_in[3];
    const float* W_IUQ   = (const float*)d_in[4];
    const float* W_w     = (const float*)d_in[5];
    const float* W_Q     = (const float*)d_in[6];
    const float* W_KV    = (const float*)d_in[7];
    const float* g_q     = (const float*)d_in[8];
    const float* g_k     = (const float*)d_in[9];
    const float* g_v     = (const float*)d_in[10];
    const float* Wg0     = (const float*)d_in[11];
    const float* bg0     = (const float*)d_in[12];
    const float* Wg1     = (const float*)d_in[13];
    const float* bg1     = (const float*)d_in[14];
    const float* Wout    = (const float*)d_in[15];
    const float* bout    = (const float*)d_in[16];

    float* ws  = (float*)d_ws;
    float* QI  = ws;                  // B*T*128   = 524288
    float* Qr  = QI + 524288;         // B*T*256   = 1048576
    float* Wiw = Qr + 1048576;        // B*T*4     = 16384
    float* KI  = Wiw + 16384;         // B*TC*32   = 32768
    float* Kb  = KI + 32768;          // B*2560*64 = 327680
    float* Vb  = Kb + 327680;         // B*2560*64 = 327680
    int* topkb = (int*)(Vb + 327680); // B*T*8

    float* outp = (float*)d_out;

    hipLaunchKernelGGL(k_phase1, dim3(1024), dim3(256), 0, stream,
                       H, W_Q, W_KV, W_DQ, W_IUQ, W_w, Wc_comp, Wc_idx,
                       g_q, g_k, g_v, QI, Wiw, Qr, KI, Kb, Vb);
    hipLaunchKernelGGL(k_score_topk, dim3((B_DIM * T_DIM) / 4), dim3(256), 0, stream,
                       QI, Wiw, KI, topkb);
    hipLaunchKernelGGL(k_attn_out, dim3((B_DIM * T_DIM) / 4), dim3(1024), 0, stream,
                       Qr, Kb, Vb, topkb, Wg0, bg0, Wg1, bg1, Wout, bout, outp);
}